// Round 1
// baseline (1737.700 us; speedup 1.0000x reference)
//
#include <hip/hip_runtime.h>
#include <hip/hip_bf16.h>
#include <math.h>
#include <cstdint>

#define KDIM 4096   // IN_FEATURES
#define ODIM 4096   // OUT_FEATURES
#define MDIM 8192   // N_ROWS
#define EPSF 1e-6f
#define TM05 2047.5f   // threshold(=2048) - 0.5

typedef __bf16 bf16x8 __attribute__((ext_vector_type(8)));
typedef float f32x4 __attribute__((ext_vector_type(4)));
typedef unsigned short u16;

__device__ __forceinline__ u16 f2bf(float f) {
  __hip_bfloat16 h = __float2bfloat16(f);
  return __builtin_bit_cast(u16, h);
}

// async global->LDS direct copy, 16 B per lane.
// LDS layout must be wave-uniform base + lane*16 (it is: tid-contiguous).
__device__ __forceinline__ void async_cp16(void* lds, const void* g) {
  __builtin_amdgcn_global_load_lds(
      (__attribute__((address_space(1))) void*)(uintptr_t)g,
      (__attribute__((address_space(3))) void*)lds, 16, 0, 0);
}

// ---------------- prep: X -> bf16 X, bf16 Y = x*(1-x) ----------------
__global__ void prep_x_kernel(const float4* __restrict__ x4,
                              ushort4* __restrict__ Xb,
                              ushort4* __restrict__ Yb) {
  int i = blockIdx.x * blockDim.x + threadIdx.x;  // exactly MDIM*KDIM/4 threads
  float4 v = x4[i];
  ushort4 xo, yo;
  xo.x = f2bf(v.x); xo.y = f2bf(v.y); xo.z = f2bf(v.z); xo.w = f2bf(v.w);
  yo.x = f2bf(v.x * (1.0f - v.x));
  yo.y = f2bf(v.y * (1.0f - v.y));
  yo.z = f2bf(v.z * (1.0f - v.z));
  yo.w = f2bf(v.w * (1.0f - v.w));
  Xb[i] = xo;
  Yb[i] = yo;
}

// ---------------- prep: W -> bf16 C=2*sig(w)-1, bf16 C2=C*C, sums ----------------
__device__ __forceinline__ void wcomp(float w, u16& cb, u16& c2b, float& sd, float& sde) {
  float pw = 1.0f / (1.0f + expf(-w));
  float c  = 2.0f * pw - 1.0f;
  float d  = 1.0f - pw;
  cb  = f2bf(c);
  c2b = f2bf(c * c);
  sd  += d;
  sde += d * pw;
}

__global__ void prep_w_kernel(const float4* __restrict__ w4,
                              ushort4* __restrict__ Cb,
                              ushort4* __restrict__ C2b,
                              float* __restrict__ sumd,
                              float* __restrict__ sumde) {
  const int o = blockIdx.x;      // one block per output feature row
  const int t = threadIdx.x;     // 256 threads
  const float4* wr = w4 + (size_t)o * (KDIM / 4);
  ushort4* cr  = Cb  + (size_t)o * (KDIM / 4);
  ushort4* c2r = C2b + (size_t)o * (KDIM / 4);
  float sd = 0.f, sde = 0.f;
#pragma unroll
  for (int it = 0; it < KDIM / 4 / 256; ++it) {
    int k4 = t + it * 256;
    float4 w = wr[k4];
    ushort4 co, c2o;
    wcomp(w.x, co.x, c2o.x, sd, sde);
    wcomp(w.y, co.y, c2o.y, sd, sde);
    wcomp(w.z, co.z, c2o.z, sd, sde);
    wcomp(w.w, co.w, c2o.w, sd, sde);
    cr[k4]  = co;
    c2r[k4] = c2o;
  }
  // wave reduce (width 64) then cross-wave via LDS
#pragma unroll
  for (int off = 32; off > 0; off >>= 1) {
    sd  += __shfl_down(sd, off);
    sde += __shfl_down(sde, off);
  }
  __shared__ float red[8];
  if ((t & 63) == 0) { red[t >> 6] = sd; red[4 + (t >> 6)] = sde; }
  __syncthreads();
  if (t == 0) {
    sumd[o]  = red[0] + red[1] + red[2] + red[3];
    sumde[o] = red[4] + red[5] + red[6] + red[7];
  }
}

// ---------------- fused dual-GEMM + erf epilogue ----------------
// mu[n][o]  = sum_k X[n][k]*C[o][k]   + sumd[o]
// var[n][o] = sum_k Y[n][k]*C2[o][k]  + sumde[o]
// out = 0.5*erfc((2047.5-mu)/(sqrt(var+eps)*sqrt2))
__global__ __launch_bounds__(256) void gemm_fused_kernel(
    const u16* __restrict__ Xb, const u16* __restrict__ Yb,
    const u16* __restrict__ Cb, const u16* __restrict__ C2b,
    const float* __restrict__ sumd, const float* __restrict__ sumde,
    float* __restrict__ out) {
  __shared__ u16 lX[128 * 32];
  __shared__ u16 lY[128 * 32];
  __shared__ u16 lC[128 * 32];
  __shared__ u16 lD[128 * 32];

  const int tid  = threadIdx.x;
  const int lane = tid & 63;
  const int wave = tid >> 6;
  const int quad = lane >> 4;
  const int r16  = lane & 15;
  const int wm = wave >> 1;   // 0..1 : 64-row strip of M within block tile
  const int wn = wave & 1;    // 0..1 : 64-col strip of O

  const int m0 = blockIdx.y * 128;
  const int n0 = blockIdx.x * 128;

  // staging: thread t covers rows {t>>2, 64+(t>>2)}, cols [(t&3)*8, +8) of each 128x32 tile
  const int srow = tid >> 2;
  const int scol = (tid & 3) * 8;
  const u16* gX0 = Xb  + (size_t)(m0 + srow) * KDIM + scol;
  const u16* gX1 = gX0 + (size_t)64 * KDIM;
  const u16* gY0 = Yb  + (size_t)(m0 + srow) * KDIM + scol;
  const u16* gY1 = gY0 + (size_t)64 * KDIM;
  const u16* gC0 = Cb  + (size_t)(n0 + srow) * KDIM + scol;
  const u16* gC1 = gC0 + (size_t)64 * KDIM;
  const u16* gD0 = C2b + (size_t)(n0 + srow) * KDIM + scol;
  const u16* gD1 = gD0 + (size_t)64 * KDIM;
  u16* lx0 = lX + tid * 8; u16* lx1 = lX + 2048 + tid * 8;
  u16* ly0 = lY + tid * 8; u16* ly1 = lY + 2048 + tid * 8;
  u16* lc0 = lC + tid * 8; u16* lc1 = lC + 2048 + tid * 8;
  u16* ld0 = lD + tid * 8; u16* ld1 = lD + 2048 + tid * 8;

  f32x4 accMu[4][4], accV[4][4];
#pragma unroll
  for (int i = 0; i < 4; ++i)
#pragma unroll
    for (int j = 0; j < 4; ++j) {
      accMu[i][j] = f32x4{0.f, 0.f, 0.f, 0.f};
      accV[i][j]  = f32x4{0.f, 0.f, 0.f, 0.f};
    }

  // fragment read offsets: A lane layout A[m=lane&15][k=(lane>>4)*8 + j]
  const int aoff = (wm * 64 + r16) * 32 + quad * 8;
  const int boff = (wn * 64 + r16) * 32 + quad * 8;

  for (int kt = 0; kt < KDIM / 32; ++kt) {
    const int kk = kt * 32;
    async_cp16(lx0, gX0 + kk); async_cp16(lx1, gX1 + kk);
    async_cp16(ly0, gY0 + kk); async_cp16(ly1, gY1 + kk);
    async_cp16(lc0, gC0 + kk); async_cp16(lc1, gC1 + kk);
    async_cp16(ld0, gD0 + kk); async_cp16(ld1, gD1 + kk);
    __syncthreads();  // compiler emits vmcnt(0) drain before barrier -> tiles ready

    bf16x8 aX[4], aY[4], bC[4], bD[4];
#pragma unroll
    for (int i = 0; i < 4; ++i) {
      aX[i] = *(const bf16x8*)(lX + aoff + i * 16 * 32);
      aY[i] = *(const bf16x8*)(lY + aoff + i * 16 * 32);
    }
#pragma unroll
    for (int j = 0; j < 4; ++j) {
      bC[j] = *(const bf16x8*)(lC + boff + j * 16 * 32);
      bD[j] = *(const bf16x8*)(lD + boff + j * 16 * 32);
    }
#pragma unroll
    for (int i = 0; i < 4; ++i)
#pragma unroll
      for (int j = 0; j < 4; ++j)
        accMu[i][j] = __builtin_amdgcn_mfma_f32_16x16x32_bf16(aX[i], bC[j], accMu[i][j], 0, 0, 0);
#pragma unroll
    for (int i = 0; i < 4; ++i)
#pragma unroll
      for (int j = 0; j < 4; ++j)
        accV[i][j] = __builtin_amdgcn_mfma_f32_16x16x32_bf16(aY[i], bD[j], accV[i][j], 0, 0, 0);
    __syncthreads();  // all waves done reading LDS before next overwrite
  }

  // epilogue: C/D layout col=lane&15, row=(lane>>4)*4+reg
  const float inv_rt2 = 0.70710678118654752f;
#pragma unroll
  for (int j = 0; j < 4; ++j) {
    const int col = n0 + wn * 64 + j * 16 + r16;
    const float sd  = sumd[col];
    const float sde = sumde[col];
#pragma unroll
    for (int i = 0; i < 4; ++i) {
      const int mrow = m0 + wm * 64 + i * 16 + quad * 4;
      f32x4 m4 = accMu[i][j];
      f32x4 v4 = accV[i][j];
#pragma unroll
      for (int r = 0; r < 4; ++r) {
        float mu  = m4[r] + sd;
        float var = v4[r] + sde + EPSF;
        float z = (TM05 - mu) * rsqrtf(var) * inv_rt2;
        out[(size_t)(mrow + r) * ODIM + col] = 0.5f * erfcf(z);
      }
    }
  }
}

// ---------------- launch ----------------
// ws layout (bytes):
//   0         : Cb   (4096*4096*2 = 33554432)
//   33554432  : C2b  (33554432)
//   67108864  : sumd (16384)
//   67125248  : sumde(16384)
//   67141632  : Xb   (8192*4096*2 = 67108864)
//   134250496 : Yb   (67108864)
//   total 201359360 B (~192 MiB)
extern "C" void kernel_launch(void* const* d_in, const int* in_sizes, int n_in,
                              void* d_out, int out_size, void* d_ws, size_t ws_size,
                              hipStream_t stream) {
  const float* p_x    = (const float*)d_in[0];
  const float* weight = (const float*)d_in[1];
  float* out = (float*)d_out;
  char* ws = (char*)d_ws;

  u16* Cb     = (u16*)(ws);
  u16* C2b    = (u16*)(ws + 33554432);
  float* sumd  = (float*)(ws + 67108864);
  float* sumde = (float*)(ws + 67125248);
  u16* Xb     = (u16*)(ws + 67141632);
  u16* Yb     = (u16*)(ws + 134250496);

  prep_w_kernel<<<ODIM, 256, 0, stream>>>((const float4*)weight, (ushort4*)Cb,
                                          (ushort4*)C2b, sumd, sumde);
  prep_x_kernel<<<(MDIM * KDIM / 4) / 256, 256, 0, stream>>>((const float4*)p_x,
                                                             (ushort4*)Xb, (ushort4*)Yb);
  dim3 grid(ODIM / 128, MDIM / 128);
  gemm_fused_kernel<<<grid, 256, 0, stream>>>(Xb, Yb, Cb, C2b, sumd, sumde, out);
}

// Round 2
// 1076.543 us; speedup vs baseline: 1.6141x; 1.6141x over previous
//
#include <hip/hip_runtime.h>
#include <hip/hip_bf16.h>
#include <math.h>
#include <cstdint>

#define KDIM 4096   // IN_FEATURES
#define ODIM 4096   // OUT_FEATURES
#define MDIM 8192   // N_ROWS
#define EPSF 1e-6f
#define TM05 2047.5f   // threshold(=2048) - 0.5

typedef __bf16 bf16x8 __attribute__((ext_vector_type(8)));
typedef float f32x4 __attribute__((ext_vector_type(4)));
typedef unsigned short u16;

// element deltas inside workspace (buffers laid out contiguously)
#define XY_DELTA (MDIM * KDIM)   // Xb -> Yb   (in u16 elements)
#define CD_DELTA (ODIM * KDIM)   // Cb -> C2b  (in u16 elements)

__device__ __forceinline__ u16 f2bf(float f) {
  __hip_bfloat16 h = __float2bfloat16(f);
  return __builtin_bit_cast(u16, h);
}

// async global->LDS direct copy, 16 B per lane (dst must be lane-linear).
__device__ __forceinline__ void async_cp16(void* lds, const void* g) {
  __builtin_amdgcn_global_load_lds(
      (__attribute__((address_space(1))) void*)(uintptr_t)g,
      (__attribute__((address_space(3))) void*)lds, 16, 0, 0);
}

// ---------------- prep: X -> bf16 X, bf16 Y = x*(1-x) ----------------
__global__ void prep_x_kernel(const float4* __restrict__ x4,
                              ushort4* __restrict__ Xb,
                              ushort4* __restrict__ Yb) {
  int i = blockIdx.x * blockDim.x + threadIdx.x;
  float4 v = x4[i];
  ushort4 xo, yo;
  xo.x = f2bf(v.x); xo.y = f2bf(v.y); xo.z = f2bf(v.z); xo.w = f2bf(v.w);
  yo.x = f2bf(v.x * (1.0f - v.x));
  yo.y = f2bf(v.y * (1.0f - v.y));
  yo.z = f2bf(v.z * (1.0f - v.z));
  yo.w = f2bf(v.w * (1.0f - v.w));
  Xb[i] = xo;
  Yb[i] = yo;
}

// ---------------- prep: W -> bf16 C=2*sig(w)-1, bf16 C2=C*C, sums ----------------
__device__ __forceinline__ void wcomp(float w, u16& cb, u16& c2b, float& sd, float& sde) {
  float pw = 1.0f / (1.0f + __expf(-w));
  float c  = 2.0f * pw - 1.0f;
  float d  = 1.0f - pw;
  cb  = f2bf(c);
  c2b = f2bf(c * c);
  sd  += d;
  sde += d * pw;
}

__global__ void prep_w_kernel(const float4* __restrict__ w4,
                              ushort4* __restrict__ Cb,
                              ushort4* __restrict__ C2b,
                              float* __restrict__ sumd,
                              float* __restrict__ sumde) {
  const int o = blockIdx.x;
  const int t = threadIdx.x;
  const float4* wr = w4 + (size_t)o * (KDIM / 4);
  ushort4* cr  = Cb  + (size_t)o * (KDIM / 4);
  ushort4* c2r = C2b + (size_t)o * (KDIM / 4);
  float sd = 0.f, sde = 0.f;
#pragma unroll
  for (int it = 0; it < KDIM / 4 / 256; ++it) {
    int k4 = t + it * 256;
    float4 w = wr[k4];
    ushort4 co, c2o;
    wcomp(w.x, co.x, c2o.x, sd, sde);
    wcomp(w.y, co.y, c2o.y, sd, sde);
    wcomp(w.z, co.z, c2o.z, sd, sde);
    wcomp(w.w, co.w, c2o.w, sd, sde);
    cr[k4]  = co;
    c2r[k4] = c2o;
  }
#pragma unroll
  for (int off = 32; off > 0; off >>= 1) {
    sd  += __shfl_down(sd, off);
    sde += __shfl_down(sde, off);
  }
  __shared__ float red[8];
  if ((t & 63) == 0) { red[t >> 6] = sd; red[4 + (t >> 6)] = sde; }
  __syncthreads();
  if (t == 0) {
    sumd[o]  = red[0] + red[1] + red[2] + red[3];
    sumde[o] = red[4] + red[5] + red[6] + red[7];
  }
}

// ---------------- fused dual-GEMM + erf epilogue ----------------
// mu[n][o]  = sum_k X[n][k]*C[o][k]   + sumd[o]
// var[n][o] = sum_k Y[n][k]*C2[o][k]  + sumde[o]
// out = 0.5*erfc((2047.5-mu)/(sqrt(var+eps)*sqrt2))
//
// LDS chunk swizzle: 16B chunk q of row r lives at slot q ^ ((r>>1)&3).
// Staging reads global chunk (c ^ ((row>>1)&3)) into lane-linear slot c;
// readers address slot (quad ^ ((r16>>1)&3)). -> 2-way bank aliasing (free).
__global__ __launch_bounds__(256, 2) void gemm_fused_kernel(
    const u16* __restrict__ Xb, const u16* __restrict__ Cb,
    const float* __restrict__ sumd, const float* __restrict__ sumde,
    float* __restrict__ out) {
  __shared__ u16 lX[128 * 32];
  __shared__ u16 lY[128 * 32];
  __shared__ u16 lC[128 * 32];
  __shared__ u16 lD[128 * 32];

  const int tid  = threadIdx.x;
  const int lane = tid & 63;
  const int wave = tid >> 6;
  const int quad = lane >> 4;
  const int r16  = lane & 15;
  const int wm = wave >> 1;
  const int wn = wave & 1;

  const int m0 = blockIdx.y * 128;
  const int n0 = blockIdx.x * 128;

  // staging: thread t covers rows {t>>2, 64+(t>>2)}; chunk slot c = t&3,
  // fetches swizzled global chunk c ^ ((srow>>1)&3). (row+64 has same swizzle.)
  const int srow = tid >> 2;
  const int c    = tid & 3;
  const int scol = (c ^ ((srow >> 1) & 3)) * 8;   // element offset of fetched chunk
  const u16* gA = Xb + (size_t)(m0 + srow) * KDIM + scol;  // X row; +XY_DELTA -> Y
  const u16* gB = Cb + (size_t)(n0 + srow) * KDIM + scol;  // C row; +CD_DELTA -> C2
  u16* lsX = lX + tid * 8;
  u16* lsY = lY + tid * 8;
  u16* lsC = lC + tid * 8;
  u16* lsD = lD + tid * 8;

  f32x4 accMu[4][4], accV[4][4];
#pragma unroll
  for (int i = 0; i < 4; ++i)
#pragma unroll
    for (int j = 0; j < 4; ++j) {
      accMu[i][j] = f32x4{0.f, 0.f, 0.f, 0.f};
      accV[i][j]  = f32x4{0.f, 0.f, 0.f, 0.f};
    }

  // fragment read offsets (u16 units), swizzled chunk select
  const int swz  = (quad ^ ((r16 >> 1) & 3)) * 8;
  const int aoff = (wm * 64 + r16) * 32 + swz;
  const int boff = (wn * 64 + r16) * 32 + swz;

  for (int kt = 0; kt < KDIM / 32; ++kt) {
    const int kk = kt * 32;
    async_cp16(lsX, gA + kk);
    async_cp16(lsX + 2048, gA + kk + 64 * KDIM);
    async_cp16(lsY, gA + kk + XY_DELTA);
    async_cp16(lsY + 2048, gA + kk + XY_DELTA + 64 * KDIM);
    async_cp16(lsC, gB + kk);
    async_cp16(lsC + 2048, gB + kk + 64 * KDIM);
    async_cp16(lsD, gB + kk + CD_DELTA);
    async_cp16(lsD + 2048, gB + kk + CD_DELTA + 64 * KDIM);
    __syncthreads();

    // ---- phase 1: mu += X * C ----
    {
      bf16x8 a[4], b[4];
#pragma unroll
      for (int i = 0; i < 4; ++i) a[i] = *(const bf16x8*)(lX + aoff + i * 16 * 32);
#pragma unroll
      for (int j = 0; j < 4; ++j) b[j] = *(const bf16x8*)(lC + boff + j * 16 * 32);
#pragma unroll
      for (int i = 0; i < 4; ++i)
#pragma unroll
        for (int j = 0; j < 4; ++j)
          accMu[i][j] = __builtin_amdgcn_mfma_f32_16x16x32_bf16(a[i], b[j], accMu[i][j], 0, 0, 0);
    }
    // ---- phase 2: var += Y * C2 ----
    {
      bf16x8 a[4], b[4];
#pragma unroll
      for (int i = 0; i < 4; ++i) a[i] = *(const bf16x8*)(lY + aoff + i * 16 * 32);
#pragma unroll
      for (int j = 0; j < 4; ++j) b[j] = *(const bf16x8*)(lD + boff + j * 16 * 32);
#pragma unroll
      for (int i = 0; i < 4; ++i)
#pragma unroll
        for (int j = 0; j < 4; ++j)
          accV[i][j] = __builtin_amdgcn_mfma_f32_16x16x32_bf16(a[i], b[j], accV[i][j], 0, 0, 0);
    }
    __syncthreads();
  }

  // epilogue: C/D layout col=lane&15, row=(lane>>4)*4+reg
  const float inv_rt2 = 0.70710678118654752f;
#pragma unroll
  for (int j = 0; j < 4; ++j) {
    const int col = n0 + wn * 64 + j * 16 + r16;
    const float sd  = sumd[col];
    const float sde = sumde[col];
#pragma unroll
    for (int i = 0; i < 4; ++i) {
      const int mrow = m0 + wm * 64 + i * 16 + quad * 4;
      f32x4 m4 = accMu[i][j];
      f32x4 v4 = accV[i][j];
#pragma unroll
      for (int r = 0; r < 4; ++r) {
        float mu  = m4[r] + sd;
        float var = v4[r] + sde + EPSF;
        float z = (TM05 - mu) * rsqrtf(var) * inv_rt2;
        out[(size_t)(mrow + r) * ODIM + col] = 0.5f * erfcf(z);
      }
    }
  }
}

// ---------------- launch ----------------
// ws layout (bytes):
//   0         : Cb   (33554432)
//   33554432  : C2b  (33554432)   = Cb + CD_DELTA elems
//   67108864  : sumd (16384)
//   67125248  : sumde(16384)
//   67141632  : Xb   (67108864)
//   134250496 : Yb   (67108864)   = Xb + XY_DELTA elems
extern "C" void kernel_launch(void* const* d_in, const int* in_sizes, int n_in,
                              void* d_out, int out_size, void* d_ws, size_t ws_size,
                              hipStream_t stream) {
  const float* p_x    = (const float*)d_in[0];
  const float* weight = (const float*)d_in[1];
  float* out = (float*)d_out;
  char* ws = (char*)d_ws;

  u16* Cb      = (u16*)(ws);
  float* sumd  = (float*)(ws + 67108864);
  float* sumde = (float*)(ws + 67125248);
  u16* Xb      = (u16*)(ws + 67141632);

  prep_w_kernel<<<ODIM, 256, 0, stream>>>((const float4*)weight, (ushort4*)Cb,
                                          (ushort4*)(ws + 33554432), sumd, sumde);
  prep_x_kernel<<<(MDIM * KDIM / 4) / 256, 256, 0, stream>>>((const float4*)p_x,
                                                             (ushort4*)Xb,
                                                             (ushort4*)(ws + 134250496));
  dim3 grid(ODIM / 128, MDIM / 128);
  gemm_fused_kernel<<<grid, 256, 0, stream>>>(Xb, Cb, sumd, sumde, out);
}

// Round 3
// 944.019 us; speedup vs baseline: 1.8407x; 1.1404x over previous
//
#include <hip/hip_runtime.h>
#include <hip/hip_bf16.h>
#include <math.h>
#include <cstdint>

#define KDIM 4096   // IN_FEATURES
#define ODIM 4096   // OUT_FEATURES
#define MDIM 8192   // N_ROWS
#define EPSF 1e-6f
#define TM05 2047.5f   // threshold(=2048) - 0.5

typedef __bf16 bf16x8 __attribute__((ext_vector_type(8)));
typedef float f32x4 __attribute__((ext_vector_type(4)));
typedef unsigned short u16;

// element deltas inside workspace (buffers laid out contiguously)
#define XY_DELTA (MDIM * KDIM)   // Xb -> Yb   (in u16 elements)
#define CD_DELTA (ODIM * KDIM)   // Cb -> C2b  (in u16 elements)

// var LDS buffer: col-major, stride 132 u16 per column (264 B: 8B-aligned,
// odd bank step -> conflict-free across r16 lanes)
#define VSTRIDE 132

__device__ __forceinline__ u16 f2bf(float f) {
  __hip_bfloat16 h = __float2bfloat16(f);
  return __builtin_bit_cast(u16, h);
}
__device__ __forceinline__ float bf2f(u16 b) {
  unsigned int u = ((unsigned int)b) << 16;
  return __builtin_bit_cast(float, u);
}

// async global->LDS direct copy, 16 B per lane (dst must be lane-linear).
__device__ __forceinline__ void async_cp16(void* lds, const void* g) {
  __builtin_amdgcn_global_load_lds(
      (__attribute__((address_space(1))) void*)(uintptr_t)g,
      (__attribute__((address_space(3))) void*)lds, 16, 0, 0);
}

// ---------------- prep: X -> bf16 X, bf16 Y = x*(1-x) ----------------
__global__ void prep_x_kernel(const float4* __restrict__ x4,
                              ushort4* __restrict__ Xb,
                              ushort4* __restrict__ Yb) {
  int i = blockIdx.x * blockDim.x + threadIdx.x;
  float4 v = x4[i];
  ushort4 xo, yo;
  xo.x = f2bf(v.x); xo.y = f2bf(v.y); xo.z = f2bf(v.z); xo.w = f2bf(v.w);
  yo.x = f2bf(v.x * (1.0f - v.x));
  yo.y = f2bf(v.y * (1.0f - v.y));
  yo.z = f2bf(v.z * (1.0f - v.z));
  yo.w = f2bf(v.w * (1.0f - v.w));
  Xb[i] = xo;
  Yb[i] = yo;
}

// ---------------- prep: W -> bf16 C=2*sig(w)-1, bf16 C2=C*C, sums ----------------
__device__ __forceinline__ void wcomp(float w, u16& cb, u16& c2b, float& sd, float& sde) {
  float pw = 1.0f / (1.0f + __expf(-w));
  float c  = 2.0f * pw - 1.0f;
  float d  = 1.0f - pw;
  cb  = f2bf(c);
  c2b = f2bf(c * c);
  sd  += d;
  sde += d * pw;
}

__global__ void prep_w_kernel(const float4* __restrict__ w4,
                              ushort4* __restrict__ Cb,
                              ushort4* __restrict__ C2b,
                              float* __restrict__ sumd,
                              float* __restrict__ sumde) {
  const int o = blockIdx.x;
  const int t = threadIdx.x;
  const float4* wr = w4 + (size_t)o * (KDIM / 4);
  ushort4* cr  = Cb  + (size_t)o * (KDIM / 4);
  ushort4* c2r = C2b + (size_t)o * (KDIM / 4);
  float sd = 0.f, sde = 0.f;
#pragma unroll
  for (int it = 0; it < KDIM / 4 / 256; ++it) {
    int k4 = t + it * 256;
    float4 w = wr[k4];
    ushort4 co, c2o;
    wcomp(w.x, co.x, c2o.x, sd, sde);
    wcomp(w.y, co.y, c2o.y, sd, sde);
    wcomp(w.z, co.z, c2o.z, sd, sde);
    wcomp(w.w, co.w, c2o.w, sd, sde);
    cr[k4]  = co;
    c2r[k4] = c2o;
  }
#pragma unroll
  for (int off = 32; off > 0; off >>= 1) {
    sd  += __shfl_down(sd, off);
    sde += __shfl_down(sde, off);
  }
  __shared__ float red[8];
  if ((t & 63) == 0) { red[t >> 6] = sd; red[4 + (t >> 6)] = sde; }
  __syncthreads();
  if (t == 0) {
    sumd[o]  = red[0] + red[1] + red[2] + red[3];
    sumde[o] = red[4] + red[5] + red[6] + red[7];
  }
}

// ---------------- fused dual-GEMM + erf epilogue (wave-specialized) ----------------
// 512 threads = 8 waves. Waves 0-3: mu = X@C^T over 128x128 tile (wave -> 64x64).
// Waves 4-7: var = Y@C2^T over the same tile. var goes through LDS (bf16) to the
// mu-waves, which apply the erfc epilogue and store.
// LDS chunk swizzle: 16B chunk q of row r lives at slot q ^ ((r>>1)&3).
__global__ __launch_bounds__(512, 4) void gemm_fused_kernel(
    const u16* __restrict__ Xb, const u16* __restrict__ Cb,
    const float* __restrict__ sumd, const float* __restrict__ sumde,
    float* __restrict__ out) {
  // tiles: lX = smem[0..4096), lY = +4096, lC = +8192, lD = +12288 (u16 units)
  // var buffer (epilogue, aliases tiles): 128 cols * VSTRIDE = 16896 u16
  __shared__ __attribute__((aligned(16))) u16 smem[128 * VSTRIDE];

  const int tid  = threadIdx.x;
  const int lane = tid & 63;
  const int wave = tid >> 6;       // 0..7
  const int grp  = wave >> 2;      // 0 = mu, 1 = var
  const int sub  = wave & 3;
  const int wm   = sub >> 1;
  const int wn   = sub & 1;
  const int quad = lane >> 4;
  const int r16  = lane & 15;

  const int m0 = blockIdx.y * 128;
  const int n0 = blockIdx.x * 128;

  // staging: thread t covers row t>>2 (0..127); chunk slot c = t&3,
  // fetches swizzled global chunk c ^ ((srow>>1)&3).
  const int srow = tid >> 2;
  const int c    = tid & 3;
  const int scol = (c ^ ((srow >> 1) & 3)) * 8;
  const u16* gA = Xb + (size_t)(m0 + srow) * KDIM + scol;  // X row; +XY_DELTA -> Y
  const u16* gB = Cb + (size_t)(n0 + srow) * KDIM + scol;  // C row; +CD_DELTA -> C2
  u16* ls = smem + tid * 8;   // lane-linear dst inside each 4096-u16 tile

  f32x4 acc[4][4];
#pragma unroll
  for (int i = 0; i < 4; ++i)
#pragma unroll
    for (int j = 0; j < 4; ++j) acc[i][j] = f32x4{0.f, 0.f, 0.f, 0.f};

  // fragment source tiles for this wave's GEMM
  const u16* aT = smem + grp * 4096;          // lX or lY
  const u16* bT = smem + 8192 + grp * 4096;   // lC or lD

  // fragment read offsets (u16 units), swizzled chunk select
  const int swz  = (quad ^ ((r16 >> 1) & 3)) * 8;
  const int aoff = (wm * 64 + r16) * 32 + swz;
  const int boff = (wn * 64 + r16) * 32 + swz;

  for (int kt = 0; kt < KDIM / 32; ++kt) {
    const int kk = kt * 32;
    async_cp16(ls,        gA + kk);             // lX
    async_cp16(ls + 4096, gA + kk + XY_DELTA);  // lY
    async_cp16(ls + 8192, gB + kk);             // lC
    async_cp16(ls + 12288, gB + kk + CD_DELTA); // lD
    __syncthreads();

    bf16x8 a[4], b[4];
#pragma unroll
    for (int i = 0; i < 4; ++i) a[i] = *(const bf16x8*)(aT + aoff + i * 16 * 32);
#pragma unroll
    for (int j = 0; j < 4; ++j) b[j] = *(const bf16x8*)(bT + boff + j * 16 * 32);
#pragma unroll
    for (int i = 0; i < 4; ++i)
#pragma unroll
      for (int j = 0; j < 4; ++j)
        acc[i][j] = __builtin_amdgcn_mfma_f32_16x16x32_bf16(a[i], b[j], acc[i][j], 0, 0, 0);
    __syncthreads();
  }

  // ---- epilogue ----
  // C/D layout: col = lane&15 (-> local col), row = quad*4 + reg (-> local row)
  if (grp) {
    // var waves: round to bf16, park in LDS col-major (stride VSTRIDE)
#pragma unroll
    for (int j = 0; j < 4; ++j) {
      const int cl = wn * 64 + j * 16 + r16;
#pragma unroll
      for (int i = 0; i < 4; ++i) {
        const int rl = wm * 64 + i * 16 + quad * 4;
        f32x4 v = acc[i][j];
        ushort4 p;
        p.x = f2bf(v[0]); p.y = f2bf(v[1]); p.z = f2bf(v[2]); p.w = f2bf(v[3]);
        *(ushort4*)(smem + cl * VSTRIDE + rl) = p;
      }
    }
  }
  __syncthreads();
  if (!grp) {
    const float inv_rt2 = 0.70710678118654752f;
#pragma unroll
    for (int j = 0; j < 4; ++j) {
      const int cl  = wn * 64 + j * 16 + r16;
      const int col = n0 + cl;
      const float sd  = sumd[col];
      const float sde = sumde[col] + EPSF;
#pragma unroll
      for (int i = 0; i < 4; ++i) {
        const int rl   = wm * 64 + i * 16 + quad * 4;
        const int mrow = m0 + rl;
        const ushort4 p = *(const ushort4*)(smem + cl * VSTRIDE + rl);
        f32x4 m4 = acc[i][j];
        const float vv[4] = {bf2f(p.x), bf2f(p.y), bf2f(p.z), bf2f(p.w)};
#pragma unroll
        for (int r = 0; r < 4; ++r) {
          float mu  = m4[r] + sd;
          float var = vv[r] + sde;
          float z = (TM05 - mu) * rsqrtf(var) * inv_rt2;
          out[(size_t)(mrow + r) * ODIM + col] = 0.5f * erfcf(z);
        }
      }
    }
  }
}

// ---------------- launch ----------------
// ws layout (bytes):
//   0         : Cb   (33554432)
//   33554432  : C2b  (33554432)   = Cb + CD_DELTA elems
//   67108864  : sumd (16384)
//   67125248  : sumde(16384)
//   67141632  : Xb   (67108864)
//   134250496 : Yb   (67108864)   = Xb + XY_DELTA elems
extern "C" void kernel_launch(void* const* d_in, const int* in_sizes, int n_in,
                              void* d_out, int out_size, void* d_ws, size_t ws_size,
                              hipStream_t stream) {
  const float* p_x    = (const float*)d_in[0];
  const float* weight = (const float*)d_in[1];
  float* out = (float*)d_out;
  char* ws = (char*)d_ws;

  u16* Cb      = (u16*)(ws);
  float* sumd  = (float*)(ws + 67108864);
  float* sumde = (float*)(ws + 67125248);
  u16* Xb      = (u16*)(ws + 67141632);

  prep_w_kernel<<<ODIM, 256, 0, stream>>>((const float4*)weight, (ushort4*)Cb,
                                          (ushort4*)(ws + 33554432), sumd, sumde);
  prep_x_kernel<<<(MDIM * KDIM / 4) / 256, 256, 0, stream>>>((const float4*)p_x,
                                                             (ushort4*)Xb,
                                                             (ushort4*)(ws + 134250496));
  dim3 grid(ODIM / 128, MDIM / 128);
  gemm_fused_kernel<<<grid, 512, 0, stream>>>(Xb, Cb, sumd, sumde, out);
}